// Round 6
// baseline (426.694 us; speedup 1.0000x reference)
//
#include <hip/hip_runtime.h>

constexpr int B = 64, N = 1500, NT = B * N;
constexpr int E_PER = 24000, E_TOT = B * E_PER;
constexpr int F_INN = 128, K = 30, TOT = 97;

// ---------------- Fused CSR build: one block per graph, CSR slice in LDS ------
__global__ __launch_bounds__(1024) void build_csr(const int* __restrict__ src, const int* __restrict__ dst,
                                                  int* __restrict__ csr, int* __restrict__ rowst,
                                                  int* __restrict__ degi, float* __restrict__ degf) {
    __shared__ int hist[N];       // counts -> cursors
    __shared__ int csr_l[E_PER];  // 96 KB CSR slice
    __shared__ int wsum[4];
    int g = blockIdx.x, t = threadIdx.x;
    int gbase = g * N;
    const int* dstg = dst + (size_t)g * E_PER;
    const int* srcg = src + (size_t)g * E_PER;

    for (int i = t; i < N; i += 1024) hist[i] = 0;
    __syncthreads();
    for (int e = t; e < E_PER; e += 1024)
        atomicAdd(&hist[dstg[e] - gbase], 1);
    __syncthreads();

    int local[6];
    int sum = 0, x = 0;
    if (t < 256) {
#pragma unroll
        for (int i = 0; i < 6; ++i) {
            int v = t * 6 + i;
            int d = (v < N) ? hist[v] : 0;
            local[i] = d;
            sum += d;
        }
        x = sum;
        int lane = t & 63;
#pragma unroll
        for (int m = 1; m < 64; m <<= 1) {
            int y = __shfl_up(x, m, 64);
            if (lane >= m) x += y;
        }
        if (lane == 63) wsum[t >> 6] = x;
    }
    __syncthreads();
    if (t < 256) {
        int woff = 0;
        int wv = t >> 6;
        for (int w = 0; w < wv; ++w) woff += wsum[w];
        int run = x - sum + woff;
#pragma unroll
        for (int i = 0; i < 6; ++i) {
            int v = t * 6 + i;
            if (v < N) {
                rowst[gbase + v] = g * E_PER + run;
                degi[gbase + v] = local[i];
                degf[gbase + v] = (float)(local[i] + 1);
                hist[v] = run;
                run += local[i];
            }
        }
    }
    __syncthreads();
    for (int e = t; e < E_PER; e += 1024) {
        int d = dstg[e] - gbase;
        int pos = atomicAdd(&hist[d], 1);
        csr_l[pos] = srcg[e];
    }
    __syncthreads();
    for (int i = t; i < E_PER; i += 1024)
        csr[(size_t)g * E_PER + i] = csr_l[i];
}

// ---------------- Tiled GEMM: t[NT,32] = h[NT,KDIM] @ W[KDIM,32] ----------------
template <int KDIM>
__global__ __launch_bounds__(256) void gemm_t(const float* __restrict__ h,
                                              const float* __restrict__ W,
                                              float* __restrict__ t) {
    __shared__ float hs[32][128];
    __shared__ float Ws[32][32];
    int tid = threadIdx.x;
    int wv = tid >> 6, lane = tid & 63;
    int v0 = blockIdx.x * 128;
    int og = wv * 8;
    float acc[2][8];
#pragma unroll
    for (int i = 0; i < 2; ++i)
#pragma unroll
        for (int j = 0; j < 8; ++j) acc[i][j] = 0.f;

    for (int kc = 0; kc < KDIM; kc += 32) {
        __syncthreads();
        {
            int n = tid >> 1, kh = (tid & 1) * 16;
            const float* hp = h + (size_t)(v0 + n) * KDIM + kc + kh;
            const float4* hp4 = reinterpret_cast<const float4*>(hp);
            float4 a = hp4[0], b = hp4[1], c = hp4[2], d = hp4[3];
            hs[kh + 0][n] = a.x;  hs[kh + 1][n] = a.y;  hs[kh + 2][n] = a.z;  hs[kh + 3][n] = a.w;
            hs[kh + 4][n] = b.x;  hs[kh + 5][n] = b.y;  hs[kh + 6][n] = b.z;  hs[kh + 7][n] = b.w;
            hs[kh + 8][n] = c.x;  hs[kh + 9][n] = c.y;  hs[kh + 10][n] = c.z; hs[kh + 11][n] = c.w;
            hs[kh + 12][n] = d.x; hs[kh + 13][n] = d.y; hs[kh + 14][n] = d.z; hs[kh + 15][n] = d.w;
        }
        {
            int r = tid >> 3, c4 = (tid & 7) * 4;
            float4 w = *reinterpret_cast<const float4*>(W + (size_t)(kc + r) * 32 + c4);
            *reinterpret_cast<float4*>(&Ws[r][c4]) = w;
        }
        __syncthreads();
#pragma unroll
        for (int k = 0; k < 32; ++k) {
            float2 hv = *reinterpret_cast<const float2*>(&hs[k][2 * lane]);
            float4 w0 = *reinterpret_cast<const float4*>(&Ws[k][og]);
            float4 w1 = *reinterpret_cast<const float4*>(&Ws[k][og + 4]);
            acc[0][0] += hv.x * w0.x; acc[0][1] += hv.x * w0.y; acc[0][2] += hv.x * w0.z; acc[0][3] += hv.x * w0.w;
            acc[0][4] += hv.x * w1.x; acc[0][5] += hv.x * w1.y; acc[0][6] += hv.x * w1.z; acc[0][7] += hv.x * w1.w;
            acc[1][0] += hv.y * w0.x; acc[1][1] += hv.y * w0.y; acc[1][2] += hv.y * w0.z; acc[1][3] += hv.y * w0.w;
            acc[1][4] += hv.y * w1.x; acc[1][5] += hv.y * w1.y; acc[1][6] += hv.y * w1.z; acc[1][7] += hv.y * w1.w;
        }
    }
#pragma unroll
    for (int i = 0; i < 2; ++i) {
        float* op = t + (size_t)(v0 + 2 * lane + i) * 32 + og;
        float4 r0 = {acc[i][0], acc[i][1], acc[i][2], acc[i][3]};
        float4 r1 = {acc[i][4], acc[i][5], acc[i][6], acc[i][7]};
        reinterpret_cast<float4*>(op)[0] = r0;
        reinterpret_cast<float4*>(op)[1] = r1;
    }
}

// ---- Aggregate, feature-quarter in LDS: block = (graph, quarter) ----
// hout[.,q*8+f] = tanh((gather+self+b)/deg); DO_W4: t4p[q][v] = partial dot
template <bool DO_W4>
__global__ __launch_bounds__(512) void agg_q(const float* __restrict__ t,
                                             const int* __restrict__ csr, const int* __restrict__ rowst,
                                             const int* __restrict__ degi, const float* __restrict__ degf,
                                             const float* __restrict__ bias, const float* __restrict__ W4,
                                             float* __restrict__ hout, float* __restrict__ t4p) {
    __shared__ float tl[N * 8]; // 48 KB feature-quarter
    int g = blockIdx.x >> 2, q = blockIdx.x & 3;
    int gbase = g * N;
    int tid = threadIdx.x;

    // stage quarter: t[gbase+v][q*8 .. q*8+8)
    const float* tg = t + (size_t)gbase * 32 + q * 8;
    for (int i = tid; i < N * 2; i += 512) {
        int v = i >> 1, j = (i & 1) * 4;
        float4 x = *reinterpret_cast<const float4*>(tg + (size_t)v * 32 + j);
        *reinterpret_cast<float4*>(&tl[v * 8 + j]) = x;
    }
    __syncthreads();

    int grp = tid >> 3, f = tid & 7; // 64 groups of 8 lanes
    int sbase = tid & 56;            // group base lane within wave
    float bf = bias[q * 8 + f];
    float w4f = DO_W4 ? W4[q * 8 + f] : 0.f;
    for (int v = grp; v < N; v += 64) {
        const int* ce = csr + rowst[gbase + v];
        int dc = degi[gbase + v];
        float acc = tl[v * 8 + f];
        for (int eb = 0; eb < dc; eb += 8) {
            int me = eb + f;
            int se = (me < dc) ? (ce[me] - gbase) : 0;
            int cnt = dc - eb;
#pragma unroll
            for (int i = 0; i < 8; ++i) {
                int s = __shfl(se, sbase + i, 64);
                float val = tl[s * 8 + f];
                if (i < cnt) acc += val;
            }
        }
        float out = tanhf((acc + bf) / degf[gbase + v]);
        hout[(size_t)(gbase + v) * 32 + q * 8 + f] = out;
        if (DO_W4) {
            float p = out * w4f;
            p += __shfl_xor(p, 4, 64);
            p += __shfl_xor(p, 2, 64);
            p += __shfl_xor(p, 1, 64);
            if (f == 0) t4p[(size_t)q * NT + gbase + v] = p;
        }
    }
}

// ---------------- Fused layer4-agg + sortpool + head: one block per graph -----
__global__ __launch_bounds__(256) void sort_head(const float* __restrict__ hc1, const float* __restrict__ hc2,
                                                 const float* __restrict__ hc3, const float* __restrict__ t4p,
                                                 const int* __restrict__ csr, const int* __restrict__ rowst,
                                                 const int* __restrict__ degi, const float* __restrict__ degf,
                                                 const float* __restrict__ b4,
                                                 const float* __restrict__ c1w, const float* __restrict__ c1b,
                                                 const float* __restrict__ c2w, const float* __restrict__ c2b,
                                                 const float* __restrict__ ow, const float* __restrict__ ob,
                                                 float* __restrict__ out) {
    __shared__ float ts[N];   // summed t4 partials
    __shared__ float vals[N]; // h4
    __shared__ unsigned long long wavetop[4][K];
    __shared__ int topk[K];
    __shared__ float pooled[K][TOT];
    __shared__ float c1[16][K];
    __shared__ float mp[16][16];
    __shared__ float dense[352];
    int g = blockIdx.x, t = threadIdx.x;
    int gbase = g * N;
    int lane = t & 63, w = t >> 6;

    // t4 = sum of 4 quarter partials (fixed order -> deterministic)
    for (int v = t; v < N; v += 256) {
        int gv = gbase + v;
        ts[v] = ((t4p[gv] + t4p[(size_t)NT + gv]) + (t4p[2 * (size_t)NT + gv] + t4p[3 * (size_t)NT + gv]));
    }
    __syncthreads();
    // layer-4 aggregation from LDS: 16-lane groups
    {
        int grp = t >> 4, f = t & 15;
        float b4v = b4[0];
        for (int v = grp; v < N; v += 16) {
            const int* ce = csr + rowst[gbase + v];
            int dc = degi[gbase + v];
            float p = 0.f;
            for (int e = f; e < dc; e += 16) p += ts[ce[e] - gbase];
            p += __shfl_xor(p, 8, 64);
            p += __shfl_xor(p, 4, 64);
            p += __shfl_xor(p, 2, 64);
            p += __shfl_xor(p, 1, 64);
            if (f == 0) vals[v] = tanhf((p + ts[v] + b4v) / degf[gbase + v]);
        }
    }
    __syncthreads();

    // wave-local top-K over 375 elements in 6 regs/lane
    unsigned long long key[6];
#pragma unroll
    for (int i = 0; i < 6; ++i) {
        int li = i * 64 + lane;
        unsigned long long kk = 0ull;
        if (li < 375) {
            int idx = w * 375 + li;
            unsigned int b = __float_as_uint(vals[idx]);
            unsigned int sk = (b & 0x80000000u) ? ~b : (b | 0x80000000u);
            kk = ((unsigned long long)sk << 32) | (unsigned int)(0x7FFFFFFF - idx);
        }
        key[i] = kk;
    }
    for (int k = 0; k < K; ++k) {
        unsigned long long m = key[0];
#pragma unroll
        for (int i = 1; i < 6; ++i) m = (key[i] > m) ? key[i] : m;
#pragma unroll
        for (int d = 32; d >= 1; d >>= 1) {
            unsigned long long o = __shfl_xor(m, d, 64);
            m = (o > m) ? o : m;
        }
#pragma unroll
        for (int i = 0; i < 6; ++i)
            if (key[i] == m) key[i] = 0ull;
        if (lane == 0) wavetop[w][k] = m;
    }
    __syncthreads();
    if (w == 0) {
        int i0 = lane, i1 = lane + 64;
        unsigned long long c0 = (i0 < 4 * K) ? wavetop[i0 / K][i0 % K] : 0ull;
        unsigned long long c1v = (i1 < 4 * K) ? wavetop[i1 / K][i1 % K] : 0ull;
        for (int k = 0; k < K; ++k) {
            unsigned long long m = (c0 > c1v) ? c0 : c1v;
#pragma unroll
            for (int d = 32; d >= 1; d >>= 1) {
                unsigned long long o = __shfl_xor(m, d, 64);
                m = (o > m) ? o : m;
            }
            if (c0 == m) c0 = 0ull;
            if (c1v == m) c1v = 0ull;
            if (lane == 0)
                topk[k] = 0x7FFFFFFF - (int)(unsigned int)(m & 0xFFFFFFFFu); // local idx
        }
    }
    __syncthreads();

    for (int i = t; i < K * TOT; i += 256) {
        int k = i / TOT, d = i % TOT;
        int gi = gbase + topk[k];
        float val = (d < 32) ? hc1[(size_t)gi * 32 + d]
                  : (d < 64) ? hc2[(size_t)gi * 32 + d - 32]
                  : (d < 96) ? hc3[(size_t)gi * 32 + d - 64]
                             : vals[topk[k]];
        pooled[k][d] = val;
    }
    __syncthreads();
    for (int i = t; i < 16 * K; i += 256) {
        int o = i / K, k = i % K;
        float s = c1b[o];
        for (int d = 0; d < TOT; ++d) s += pooled[k][d] * c1w[o * TOT + d];
        c1[o][k] = fmaxf(s, 0.f);
    }
    __syncthreads();
    for (int i = t; i < 16 * 15; i += 256) {
        int o = i / 15, p = i % 15;
        mp[o][p] = fmaxf(c1[o][2 * p], c1[o][2 * p + 1]);
    }
    __syncthreads();
    for (int i = t; i < 352; i += 256) {
        int o = i / 11, p = i % 11;
        float s = c2b[o];
#pragma unroll
        for (int ci = 0; ci < 16; ++ci)
#pragma unroll
            for (int tt = 0; tt < 5; ++tt)
                s += mp[ci][p + tt] * c2w[(o * 16 + ci) * 5 + tt];
        dense[i] = fmaxf(s, 0.f);
    }
    __syncthreads();
    if (t < 128) {
        float s = ob[t];
        for (int m = 0; m < 352; ++m) s += dense[m] * ow[m * 128 + t];
        out[g * 128 + t] = fmaxf(s, 0.f);
    }
}

extern "C" void kernel_launch(void* const* d_in, const int* in_sizes, int n_in,
                              void* d_out, int out_size, void* d_ws, size_t ws_size,
                              hipStream_t stream) {
    const float* node_feat = (const float*)d_in[0];
    const int* esrc = (const int*)d_in[1];
    const int* edst = (const int*)d_in[2];
    const float* W1 = (const float*)d_in[3];
    const float* b1 = (const float*)d_in[4];
    const float* W2 = (const float*)d_in[5];
    const float* b2 = (const float*)d_in[6];
    const float* W3 = (const float*)d_in[7];
    const float* b3 = (const float*)d_in[8];
    const float* W4 = (const float*)d_in[9];
    const float* b4 = (const float*)d_in[10];
    const float* c1w = (const float*)d_in[11];
    const float* c1b = (const float*)d_in[12];
    const float* c2w = (const float*)d_in[13];
    const float* c2b = (const float*)d_in[14];
    const float* ow = (const float*)d_in[15];
    const float* ob = (const float*)d_in[16];

    char* ws = (char*)d_ws;
    size_t off = 0;
    auto alloc = [&](size_t bytes) {
        size_t r = off;
        off += (bytes + 255) & ~(size_t)255;
        return r;
    };
    int* deg_i = (int*)(ws + alloc((size_t)NT * 4));
    int* rowst = (int*)(ws + alloc((size_t)NT * 4));
    float* degf = (float*)(ws + alloc((size_t)NT * 4));
    int* csr = (int*)(ws + alloc((size_t)E_TOT * 4));
    float* tA = (float*)(ws + alloc((size_t)NT * 32 * 4));
    float* tB = (float*)(ws + alloc((size_t)NT * 32 * 4));
    float* hc1 = (float*)(ws + alloc((size_t)NT * 32 * 4));
    float* hc2 = (float*)(ws + alloc((size_t)NT * 32 * 4));
    float* hc3 = (float*)(ws + alloc((size_t)NT * 32 * 4));
    float* t4p = (float*)(ws + alloc((size_t)4 * NT * 4));

    build_csr<<<B, 1024, 0, stream>>>(esrc, edst, csr, rowst, deg_i, degf);

    gemm_t<F_INN><<<NT / 128, 256, 0, stream>>>(node_feat, W1, tA);
    agg_q<false><<<B * 4, 512, 0, stream>>>(tA, csr, rowst, deg_i, degf, b1, nullptr, hc1, nullptr);
    gemm_t<32><<<NT / 128, 256, 0, stream>>>(hc1, W2, tB);
    agg_q<false><<<B * 4, 512, 0, stream>>>(tB, csr, rowst, deg_i, degf, b2, nullptr, hc2, nullptr);
    gemm_t<32><<<NT / 128, 256, 0, stream>>>(hc2, W3, tA);
    agg_q<true><<<B * 4, 512, 0, stream>>>(tA, csr, rowst, deg_i, degf, b3, W4, hc3, t4p);

    sort_head<<<B, 256, 0, stream>>>(hc1, hc2, hc3, t4p, csr, rowst, deg_i, degf, b4,
                                     c1w, c1b, c2w, c2b, ow, ob, (float*)d_out);
}

// Round 7
// 188.715 us; speedup vs baseline: 2.2611x; 2.2611x over previous
//
#include <hip/hip_runtime.h>

constexpr int B = 64, N = 1500, NT = B * N;
constexpr int E_PER = 24000, E_TOT = B * E_PER;
constexpr int F_INN = 128, K = 30, TOT = 97;
constexpr int NB_G = 188; // blocks per graph in agg_f (188*8 >= 1500)

// ---------------- Fused CSR build: one block per graph, CSR slice in LDS ------
__global__ __launch_bounds__(1024) void build_csr(const int* __restrict__ src, const int* __restrict__ dst,
                                                  int* __restrict__ csr, int* __restrict__ rowst,
                                                  int* __restrict__ degi, float* __restrict__ degf) {
    __shared__ int hist[N];       // counts -> cursors
    __shared__ int csr_l[E_PER];  // 96 KB CSR slice
    __shared__ int wsum[4];
    int g = blockIdx.x, t = threadIdx.x;
    int gbase = g * N;
    const int* dstg = dst + (size_t)g * E_PER;
    const int* srcg = src + (size_t)g * E_PER;

    for (int i = t; i < N; i += 1024) hist[i] = 0;
    __syncthreads();
    for (int e = t; e < E_PER; e += 1024)
        atomicAdd(&hist[dstg[e] - gbase], 1);
    __syncthreads();

    int local[6];
    int sum = 0, x = 0;
    if (t < 256) {
#pragma unroll
        for (int i = 0; i < 6; ++i) {
            int v = t * 6 + i;
            int d = (v < N) ? hist[v] : 0;
            local[i] = d;
            sum += d;
        }
        x = sum;
        int lane = t & 63;
#pragma unroll
        for (int m = 1; m < 64; m <<= 1) {
            int y = __shfl_up(x, m, 64);
            if (lane >= m) x += y;
        }
        if (lane == 63) wsum[t >> 6] = x;
    }
    __syncthreads();
    if (t < 256) {
        int woff = 0;
        int wv = t >> 6;
        for (int w = 0; w < wv; ++w) woff += wsum[w];
        int run = x - sum + woff;
#pragma unroll
        for (int i = 0; i < 6; ++i) {
            int v = t * 6 + i;
            if (v < N) {
                rowst[gbase + v] = g * E_PER + run;
                degi[gbase + v] = local[i];
                degf[gbase + v] = (float)(local[i] + 1);
                hist[v] = run;
                run += local[i];
            }
        }
    }
    __syncthreads();
    for (int e = t; e < E_PER; e += 1024) {
        int d = dstg[e] - gbase;
        int pos = atomicAdd(&hist[d], 1);
        csr_l[pos] = srcg[e];
    }
    __syncthreads();
    for (int i = t; i < E_PER; i += 1024)
        csr[(size_t)g * E_PER + i] = csr_l[i];
}

// ---------------- Tiled GEMM: t[NT,32] = h[NT,128] @ W[128,32] ----------------
template <int KDIM>
__global__ __launch_bounds__(256) void gemm_t(const float* __restrict__ h,
                                              const float* __restrict__ W,
                                              float* __restrict__ t) {
    __shared__ float hs[32][128];
    __shared__ float Ws[32][32];
    int tid = threadIdx.x;
    int wv = tid >> 6, lane = tid & 63;
    int v0 = blockIdx.x * 128;
    int og = wv * 8;
    float acc[2][8];
#pragma unroll
    for (int i = 0; i < 2; ++i)
#pragma unroll
        for (int j = 0; j < 8; ++j) acc[i][j] = 0.f;

    for (int kc = 0; kc < KDIM; kc += 32) {
        __syncthreads();
        {
            int n = tid >> 1, kh = (tid & 1) * 16;
            const float* hp = h + (size_t)(v0 + n) * KDIM + kc + kh;
            const float4* hp4 = reinterpret_cast<const float4*>(hp);
            float4 a = hp4[0], b = hp4[1], c = hp4[2], d = hp4[3];
            hs[kh + 0][n] = a.x;  hs[kh + 1][n] = a.y;  hs[kh + 2][n] = a.z;  hs[kh + 3][n] = a.w;
            hs[kh + 4][n] = b.x;  hs[kh + 5][n] = b.y;  hs[kh + 6][n] = b.z;  hs[kh + 7][n] = b.w;
            hs[kh + 8][n] = c.x;  hs[kh + 9][n] = c.y;  hs[kh + 10][n] = c.z; hs[kh + 11][n] = c.w;
            hs[kh + 12][n] = d.x; hs[kh + 13][n] = d.y; hs[kh + 14][n] = d.z; hs[kh + 15][n] = d.w;
        }
        {
            int r = tid >> 3, c4 = (tid & 7) * 4;
            float4 w = *reinterpret_cast<const float4*>(W + (size_t)(kc + r) * 32 + c4);
            *reinterpret_cast<float4*>(&Ws[r][c4]) = w;
        }
        __syncthreads();
#pragma unroll
        for (int k = 0; k < 32; ++k) {
            float2 hv = *reinterpret_cast<const float2*>(&hs[k][2 * lane]);
            float4 w0 = *reinterpret_cast<const float4*>(&Ws[k][og]);
            float4 w1 = *reinterpret_cast<const float4*>(&Ws[k][og + 4]);
            acc[0][0] += hv.x * w0.x; acc[0][1] += hv.x * w0.y; acc[0][2] += hv.x * w0.z; acc[0][3] += hv.x * w0.w;
            acc[0][4] += hv.x * w1.x; acc[0][5] += hv.x * w1.y; acc[0][6] += hv.x * w1.z; acc[0][7] += hv.x * w1.w;
            acc[1][0] += hv.y * w0.x; acc[1][1] += hv.y * w0.y; acc[1][2] += hv.y * w0.z; acc[1][3] += hv.y * w0.w;
            acc[1][4] += hv.y * w1.x; acc[1][5] += hv.y * w1.y; acc[1][6] += hv.y * w1.z; acc[1][7] += hv.y * w1.w;
        }
    }
#pragma unroll
    for (int i = 0; i < 2; ++i) {
        float* op = t + (size_t)(v0 + 2 * lane + i) * 32 + og;
        float4 r0 = {acc[i][0], acc[i][1], acc[i][2], acc[i][3]};
        float4 r1 = {acc[i][4], acc[i][5], acc[i][6], acc[i][7]};
        reinterpret_cast<float4*>(op)[0] = r0;
        reinterpret_cast<float4*>(op)[1] = r1;
    }
}

// ---- Aggregate 32-wide + fused next-layer transform; XCD-swizzled blocks ----
// Graph g owned by XCD (g&7): bid -> xcd = bid&7, j = bid>>3, g = xcd + 8*(j/NB_G)
// hout = tanh((gather(t)+self+b)/deg); FUSE=32: tn = hout@Wn; FUSE=1: tn = hout.Wn
template <int FUSE>
__global__ __launch_bounds__(256) void agg_f(const float* __restrict__ t,
                                             const int* __restrict__ csr, const int* __restrict__ rowst,
                                             const int* __restrict__ degi, const float* __restrict__ degf,
                                             const float* __restrict__ bias, const float* __restrict__ Wn,
                                             float* __restrict__ hout, float* __restrict__ tn) {
    __shared__ float Ws[1024];
    __shared__ float outs[8][32];
    if (FUSE == 32) {
        for (int i = threadIdx.x; i < 1024; i += 256) Ws[i] = Wn[i];
    }
    int bid = blockIdx.x;
    int xcd = bid & 7, j = bid >> 3;
    int g = xcd + 8 * (j / NB_G);
    int nb = j % NB_G;
    int hw = threadIdx.x >> 5;
    int f = threadIdx.x & 31;
    int vl = nb * 8 + hw;
    bool valid = vl < N;
    int v = g * N + vl;
    float out = 0.f;
    if (valid) {
        const float* tp = t + f;
        float acc = tp[(size_t)v * 32];
        int e0 = rowst[v], dc = degi[v];
        float a0 = 0.f, a1 = 0.f, a2 = 0.f, a3 = 0.f, a4 = 0.f, a5 = 0.f, a6 = 0.f, a7 = 0.f;
        int e = 0;
        for (; e + 8 <= dc; e += 8) {
            int s0 = csr[e0 + e], s1 = csr[e0 + e + 1], s2 = csr[e0 + e + 2], s3 = csr[e0 + e + 3];
            int s4 = csr[e0 + e + 4], s5 = csr[e0 + e + 5], s6 = csr[e0 + e + 6], s7 = csr[e0 + e + 7];
            a0 += tp[(size_t)s0 * 32];
            a1 += tp[(size_t)s1 * 32];
            a2 += tp[(size_t)s2 * 32];
            a3 += tp[(size_t)s3 * 32];
            a4 += tp[(size_t)s4 * 32];
            a5 += tp[(size_t)s5 * 32];
            a6 += tp[(size_t)s6 * 32];
            a7 += tp[(size_t)s7 * 32];
        }
        for (; e < dc; ++e) a0 += tp[(size_t)csr[e0 + e] * 32];
        acc += ((a0 + a1) + (a2 + a3)) + ((a4 + a5) + (a6 + a7));
        out = tanhf((acc + bias[f]) / degf[v]);
        hout[(size_t)v * 32 + f] = out;
    }
    if (FUSE == 32) {
        outs[hw][f] = out;
        __syncthreads();
        if (valid) {
            float s = 0.f;
#pragma unroll
            for (int ff = 0; ff < 32; ++ff) s += outs[hw][ff] * Ws[ff * 32 + f];
            tn[(size_t)v * 32 + f] = s;
        }
    } else if (valid) {
        float p = out * Wn[f];
#pragma unroll
        for (int m = 16; m >= 1; m >>= 1) p += __shfl_xor(p, m, 64);
        if (f == 0) tn[v] = p;
    }
}

// ---------------- Layer-4 aggregate: scalar gather ----------------
__global__ __launch_bounds__(256) void agg1f(const float* __restrict__ t4,
                                             const int* __restrict__ csr, const int* __restrict__ rowst,
                                             const int* __restrict__ degi, const float* __restrict__ degf,
                                             const float* __restrict__ b4, float* __restrict__ h4) {
    int v = blockIdx.x * 256 + threadIdx.x;
    if (v >= NT) return;
    float acc = t4[v];
    int e0 = rowst[v], dc = degi[v];
    float a0 = 0.f, a1 = 0.f, a2 = 0.f, a3 = 0.f;
    int e = 0;
    for (; e + 4 <= dc; e += 4) {
        a0 += t4[csr[e0 + e]];
        a1 += t4[csr[e0 + e + 1]];
        a2 += t4[csr[e0 + e + 2]];
        a3 += t4[csr[e0 + e + 3]];
    }
    for (; e < dc; ++e) a0 += t4[csr[e0 + e]];
    acc += (a0 + a1) + (a2 + a3);
    h4[v] = tanhf((acc + b4[0]) / degf[v]);
}

// ---------------- Fused sortpool + head: one block per graph ----------------
// top-K via register-resident uint64 keys: (sortable(val)<<32)|(0x7FFFFFFF-idx)
__global__ __launch_bounds__(256) void sort_head(const float* __restrict__ hc1, const float* __restrict__ hc2,
                                                 const float* __restrict__ hc3, const float* __restrict__ h4,
                                                 const float* __restrict__ c1w, const float* __restrict__ c1b,
                                                 const float* __restrict__ c2w, const float* __restrict__ c2b,
                                                 const float* __restrict__ ow, const float* __restrict__ ob,
                                                 float* __restrict__ out) {
    __shared__ unsigned long long wavetop[4][K];
    __shared__ int topk[K];
    __shared__ float pooled[K][TOT];
    __shared__ float c1[16][K];
    __shared__ float mp[16][16];
    __shared__ float dense[352];
    int g = blockIdx.x, t = threadIdx.x;
    int lane = t & 63, w = t >> 6;

    // wave-local top-K over 375 elements held in 6 regs/lane (no barriers)
    unsigned long long key[6];
    const float* hp = h4 + (size_t)g * N + w * 375;
#pragma unroll
    for (int i = 0; i < 6; ++i) {
        int li = i * 64 + lane;
        unsigned long long kk = 0ull;
        if (li < 375) {
            unsigned int b = __float_as_uint(hp[li]);
            unsigned int sk = (b & 0x80000000u) ? ~b : (b | 0x80000000u);
            kk = ((unsigned long long)sk << 32) | (unsigned int)(0x7FFFFFFF - (w * 375 + li));
        }
        key[i] = kk;
    }
    for (int k = 0; k < K; ++k) {
        unsigned long long m = key[0];
#pragma unroll
        for (int i = 1; i < 6; ++i) m = (key[i] > m) ? key[i] : m;
#pragma unroll
        for (int d = 32; d >= 1; d >>= 1) {
            unsigned long long o = __shfl_xor(m, d, 64);
            m = (o > m) ? o : m;
        }
#pragma unroll
        for (int i = 0; i < 6; ++i)
            if (key[i] == m) key[i] = 0ull;
        if (lane == 0) wavetop[w][k] = m;
    }
    __syncthreads();
    // merge 4x30 candidates on wave 0
    if (w == 0) {
        int i0 = lane, i1 = lane + 64;
        unsigned long long c0 = (i0 < 4 * K) ? wavetop[i0 / K][i0 % K] : 0ull;
        unsigned long long c1v = (i1 < 4 * K) ? wavetop[i1 / K][i1 % K] : 0ull;
        for (int k = 0; k < K; ++k) {
            unsigned long long m = (c0 > c1v) ? c0 : c1v;
#pragma unroll
            for (int d = 32; d >= 1; d >>= 1) {
                unsigned long long o = __shfl_xor(m, d, 64);
                m = (o > m) ? o : m;
            }
            if (c0 == m) c0 = 0ull;
            if (c1v == m) c1v = 0ull;
            if (lane == 0)
                topk[k] = g * N + (0x7FFFFFFF - (int)(unsigned int)(m & 0xFFFFFFFFu));
        }
    }
    __syncthreads();

    for (int i = t; i < K * TOT; i += 256) {
        int k = i / TOT, d = i % TOT;
        int gi = topk[k];
        float val = (d < 32) ? hc1[(size_t)gi * 32 + d]
                  : (d < 64) ? hc2[(size_t)gi * 32 + d - 32]
                  : (d < 96) ? hc3[(size_t)gi * 32 + d - 64]
                             : h4[gi];
        pooled[k][d] = val;
    }
    __syncthreads();
    for (int i = t; i < 16 * K; i += 256) {
        int o = i / K, k = i % K;
        float s = c1b[o];
        for (int d = 0; d < TOT; ++d) s += pooled[k][d] * c1w[o * TOT + d];
        c1[o][k] = fmaxf(s, 0.f);
    }
    __syncthreads();
    for (int i = t; i < 16 * 15; i += 256) {
        int o = i / 15, p = i % 15;
        mp[o][p] = fmaxf(c1[o][2 * p], c1[o][2 * p + 1]);
    }
    __syncthreads();
    for (int i = t; i < 352; i += 256) {
        int o = i / 11, p = i % 11;
        float s = c2b[o];
#pragma unroll
        for (int ci = 0; ci < 16; ++ci)
#pragma unroll
            for (int tt = 0; tt < 5; ++tt)
                s += mp[ci][p + tt] * c2w[(o * 16 + ci) * 5 + tt];
        dense[i] = fmaxf(s, 0.f);
    }
    __syncthreads();
    if (t < 128) {
        float s = ob[t];
        for (int m = 0; m < 352; ++m) s += dense[m] * ow[m * 128 + t];
        out[g * 128 + t] = fmaxf(s, 0.f);
    }
}

extern "C" void kernel_launch(void* const* d_in, const int* in_sizes, int n_in,
                              void* d_out, int out_size, void* d_ws, size_t ws_size,
                              hipStream_t stream) {
    const float* node_feat = (const float*)d_in[0];
    const int* esrc = (const int*)d_in[1];
    const int* edst = (const int*)d_in[2];
    const float* W1 = (const float*)d_in[3];
    const float* b1 = (const float*)d_in[4];
    const float* W2 = (const float*)d_in[5];
    const float* b2 = (const float*)d_in[6];
    const float* W3 = (const float*)d_in[7];
    const float* b3 = (const float*)d_in[8];
    const float* W4 = (const float*)d_in[9];
    const float* b4 = (const float*)d_in[10];
    const float* c1w = (const float*)d_in[11];
    const float* c1b = (const float*)d_in[12];
    const float* c2w = (const float*)d_in[13];
    const float* c2b = (const float*)d_in[14];
    const float* ow = (const float*)d_in[15];
    const float* ob = (const float*)d_in[16];

    char* ws = (char*)d_ws;
    size_t off = 0;
    auto alloc = [&](size_t bytes) {
        size_t r = off;
        off += (bytes + 255) & ~(size_t)255;
        return r;
    };
    int* deg_i = (int*)(ws + alloc((size_t)NT * 4));
    int* rowst = (int*)(ws + alloc((size_t)NT * 4));
    float* degf = (float*)(ws + alloc((size_t)NT * 4));
    int* csr = (int*)(ws + alloc((size_t)E_TOT * 4));
    float* tA = (float*)(ws + alloc((size_t)NT * 32 * 4));
    float* tB = (float*)(ws + alloc((size_t)NT * 32 * 4));
    float* hc1 = (float*)(ws + alloc((size_t)NT * 32 * 4));
    float* hc2 = (float*)(ws + alloc((size_t)NT * 32 * 4));
    float* hc3 = (float*)(ws + alloc((size_t)NT * 32 * 4));
    float* t4 = (float*)(ws + alloc((size_t)NT * 4));
    float* h4 = (float*)(ws + alloc((size_t)NT * 4));

    build_csr<<<B, 1024, 0, stream>>>(esrc, edst, csr, rowst, deg_i, degf);

    gemm_t<F_INN><<<NT / 128, 256, 0, stream>>>(node_feat, W1, tA);
    agg_f<32><<<8 * NB_G * 8, 256, 0, stream>>>(tA, csr, rowst, deg_i, degf, b1, W2, hc1, tB);
    agg_f<32><<<8 * NB_G * 8, 256, 0, stream>>>(tB, csr, rowst, deg_i, degf, b2, W3, hc2, tA);
    agg_f<1><<<8 * NB_G * 8, 256, 0, stream>>>(tA, csr, rowst, deg_i, degf, b3, W4, hc3, t4);
    agg1f<<<(NT + 255) / 256, 256, 0, stream>>>(t4, csr, rowst, deg_i, degf, b4, h4);

    sort_head<<<B, 256, 0, stream>>>(hc1, hc2, hc3, h4, c1w, c1b, c2w, c2b, ow, ob, (float*)d_out);
}

// Round 8
// 169.880 us; speedup vs baseline: 2.5117x; 1.1109x over previous
//
#include <hip/hip_runtime.h>

constexpr int B = 64, N = 1500, NT = B * N;
constexpr int E_PER = 24000, E_TOT = B * E_PER;
constexpr int F_INN = 128, K = 30, TOT = 97;
constexpr int NB_G = 188; // blocks per graph in agg_f (188*8 >= 1500)

// ---------------- Fused CSR build: one block per graph, CSR slice in LDS ------
__global__ __launch_bounds__(1024) void build_csr(const int* __restrict__ src, const int* __restrict__ dst,
                                                  int* __restrict__ csr, int* __restrict__ rowst,
                                                  int* __restrict__ degi, float* __restrict__ degf) {
    __shared__ int hist[N];       // counts -> cursors
    __shared__ int csr_l[E_PER];  // 96 KB CSR slice
    __shared__ int wsum[4];
    int g = blockIdx.x, t = threadIdx.x;
    int gbase = g * N;
    const int* dstg = dst + (size_t)g * E_PER;
    const int* srcg = src + (size_t)g * E_PER;

    for (int i = t; i < N; i += 1024) hist[i] = 0;
    __syncthreads();
    for (int e = t; e < E_PER; e += 1024)
        atomicAdd(&hist[dstg[e] - gbase], 1);
    __syncthreads();

    int local[6];
    int sum = 0, x = 0;
    if (t < 256) {
#pragma unroll
        for (int i = 0; i < 6; ++i) {
            int v = t * 6 + i;
            int d = (v < N) ? hist[v] : 0;
            local[i] = d;
            sum += d;
        }
        x = sum;
        int lane = t & 63;
#pragma unroll
        for (int m = 1; m < 64; m <<= 1) {
            int y = __shfl_up(x, m, 64);
            if (lane >= m) x += y;
        }
        if (lane == 63) wsum[t >> 6] = x;
    }
    __syncthreads();
    if (t < 256) {
        int woff = 0;
        int wv = t >> 6;
        for (int w = 0; w < wv; ++w) woff += wsum[w];
        int run = x - sum + woff;
#pragma unroll
        for (int i = 0; i < 6; ++i) {
            int v = t * 6 + i;
            if (v < N) {
                rowst[gbase + v] = g * E_PER + run;
                degi[gbase + v] = local[i];
                degf[gbase + v] = (float)(local[i] + 1);
                hist[v] = run;
                run += local[i];
            }
        }
    }
    __syncthreads();
    for (int e = t; e < E_PER; e += 1024) {
        int d = dstg[e] - gbase;
        int pos = atomicAdd(&hist[d], 1);
        csr_l[pos] = srcg[e];
    }
    __syncthreads();
    for (int i = t; i < E_PER; i += 1024)
        csr[(size_t)g * E_PER + i] = csr_l[i];
}

// ---------------- Tiled GEMM: t[NT,32] = h[NT,128] @ W[128,32] ----------------
template <int KDIM>
__global__ __launch_bounds__(256) void gemm_t(const float* __restrict__ h,
                                              const float* __restrict__ W,
                                              float* __restrict__ t) {
    __shared__ float hs[32][128];
    __shared__ float Ws[32][32];
    int tid = threadIdx.x;
    int wv = tid >> 6, lane = tid & 63;
    int v0 = blockIdx.x * 128;
    int og = wv * 8;
    float acc[2][8];
#pragma unroll
    for (int i = 0; i < 2; ++i)
#pragma unroll
        for (int j = 0; j < 8; ++j) acc[i][j] = 0.f;

    for (int kc = 0; kc < KDIM; kc += 32) {
        __syncthreads();
        {
            int n = tid >> 1, kh = (tid & 1) * 16;
            const float* hp = h + (size_t)(v0 + n) * KDIM + kc + kh;
            const float4* hp4 = reinterpret_cast<const float4*>(hp);
            float4 a = hp4[0], b = hp4[1], c = hp4[2], d = hp4[3];
            hs[kh + 0][n] = a.x;  hs[kh + 1][n] = a.y;  hs[kh + 2][n] = a.z;  hs[kh + 3][n] = a.w;
            hs[kh + 4][n] = b.x;  hs[kh + 5][n] = b.y;  hs[kh + 6][n] = b.z;  hs[kh + 7][n] = b.w;
            hs[kh + 8][n] = c.x;  hs[kh + 9][n] = c.y;  hs[kh + 10][n] = c.z; hs[kh + 11][n] = c.w;
            hs[kh + 12][n] = d.x; hs[kh + 13][n] = d.y; hs[kh + 14][n] = d.z; hs[kh + 15][n] = d.w;
        }
        {
            int r = tid >> 3, c4 = (tid & 7) * 4;
            float4 w = *reinterpret_cast<const float4*>(W + (size_t)(kc + r) * 32 + c4);
            *reinterpret_cast<float4*>(&Ws[r][c4]) = w;
        }
        __syncthreads();
#pragma unroll
        for (int k = 0; k < 32; ++k) {
            float2 hv = *reinterpret_cast<const float2*>(&hs[k][2 * lane]);
            float4 w0 = *reinterpret_cast<const float4*>(&Ws[k][og]);
            float4 w1 = *reinterpret_cast<const float4*>(&Ws[k][og + 4]);
            acc[0][0] += hv.x * w0.x; acc[0][1] += hv.x * w0.y; acc[0][2] += hv.x * w0.z; acc[0][3] += hv.x * w0.w;
            acc[0][4] += hv.x * w1.x; acc[0][5] += hv.x * w1.y; acc[0][6] += hv.x * w1.z; acc[0][7] += hv.x * w1.w;
            acc[1][0] += hv.y * w0.x; acc[1][1] += hv.y * w0.y; acc[1][2] += hv.y * w0.z; acc[1][3] += hv.y * w0.w;
            acc[1][4] += hv.y * w1.x; acc[1][5] += hv.y * w1.y; acc[1][6] += hv.y * w1.z; acc[1][7] += hv.y * w1.w;
        }
    }
#pragma unroll
    for (int i = 0; i < 2; ++i) {
        float* op = t + (size_t)(v0 + 2 * lane + i) * 32 + og;
        float4 r0 = {acc[i][0], acc[i][1], acc[i][2], acc[i][3]};
        float4 r1 = {acc[i][4], acc[i][5], acc[i][6], acc[i][7]};
        reinterpret_cast<float4*>(op)[0] = r0;
        reinterpret_cast<float4*>(op)[1] = r1;
    }
}

// ---- Aggregate 32-wide + fused next-layer transform; XCD-swizzled blocks ----
template <int FUSE>
__global__ __launch_bounds__(256) void agg_f(const float* __restrict__ t,
                                             const int* __restrict__ csr, const int* __restrict__ rowst,
                                             const int* __restrict__ degi, const float* __restrict__ degf,
                                             const float* __restrict__ bias, const float* __restrict__ Wn,
                                             float* __restrict__ hout, float* __restrict__ tn) {
    __shared__ float Ws[1024];
    __shared__ float outs[8][32];
    if (FUSE == 32) {
        for (int i = threadIdx.x; i < 1024; i += 256) Ws[i] = Wn[i];
    }
    int bid = blockIdx.x;
    int xcd = bid & 7, j = bid >> 3;
    int g = xcd + 8 * (j / NB_G);
    int nb = j % NB_G;
    int hw = threadIdx.x >> 5;
    int f = threadIdx.x & 31;
    int vl = nb * 8 + hw;
    bool valid = vl < N;
    int v = g * N + vl;
    float out = 0.f;
    if (valid) {
        const float* tp = t + f;
        float acc = tp[(size_t)v * 32];
        int e0 = rowst[v], dc = degi[v];
        float a0 = 0.f, a1 = 0.f, a2 = 0.f, a3 = 0.f, a4 = 0.f, a5 = 0.f, a6 = 0.f, a7 = 0.f;
        int e = 0;
        for (; e + 8 <= dc; e += 8) {
            int s0 = csr[e0 + e], s1 = csr[e0 + e + 1], s2 = csr[e0 + e + 2], s3 = csr[e0 + e + 3];
            int s4 = csr[e0 + e + 4], s5 = csr[e0 + e + 5], s6 = csr[e0 + e + 6], s7 = csr[e0 + e + 7];
            a0 += tp[(size_t)s0 * 32];
            a1 += tp[(size_t)s1 * 32];
            a2 += tp[(size_t)s2 * 32];
            a3 += tp[(size_t)s3 * 32];
            a4 += tp[(size_t)s4 * 32];
            a5 += tp[(size_t)s5 * 32];
            a6 += tp[(size_t)s6 * 32];
            a7 += tp[(size_t)s7 * 32];
        }
        for (; e < dc; ++e) a0 += tp[(size_t)csr[e0 + e] * 32];
        acc += ((a0 + a1) + (a2 + a3)) + ((a4 + a5) + (a6 + a7));
        out = tanhf((acc + bias[f]) / degf[v]);
        hout[(size_t)v * 32 + f] = out;
    }
    if (FUSE == 32) {
        outs[hw][f] = out;
        __syncthreads();
        if (valid) {
            float s = 0.f;
#pragma unroll
            for (int ff = 0; ff < 32; ++ff) s += outs[hw][ff] * Ws[ff * 32 + f];
            tn[(size_t)v * 32 + f] = s;
        }
    } else if (valid) {
        float p = out * Wn[f];
#pragma unroll
        for (int m = 16; m >= 1; m >>= 1) p += __shfl_xor(p, m, 64);
        if (f == 0) tn[v] = p;
    }
}

// ---------------- Layer-4 aggregate: scalar gather ----------------
__global__ __launch_bounds__(256) void agg1f(const float* __restrict__ t4,
                                             const int* __restrict__ csr, const int* __restrict__ rowst,
                                             const int* __restrict__ degi, const float* __restrict__ degf,
                                             const float* __restrict__ b4, float* __restrict__ h4) {
    int v = blockIdx.x * 256 + threadIdx.x;
    if (v >= NT) return;
    float acc = t4[v];
    int e0 = rowst[v], dc = degi[v];
    float a0 = 0.f, a1 = 0.f, a2 = 0.f, a3 = 0.f;
    int e = 0;
    for (; e + 4 <= dc; e += 4) {
        a0 += t4[csr[e0 + e]];
        a1 += t4[csr[e0 + e + 1]];
        a2 += t4[csr[e0 + e + 2]];
        a3 += t4[csr[e0 + e + 3]];
    }
    for (; e < dc; ++e) a0 += t4[csr[e0 + e]];
    acc += (a0 + a1) + (a2 + a3);
    h4[v] = tanhf((acc + b4[0]) / degf[v]);
}

// -------- Fused sortpool (radix top-K) + head: one 512-thread block/graph -----
__global__ __launch_bounds__(512) void sort_head(const float* __restrict__ hc1, const float* __restrict__ hc2,
                                                 const float* __restrict__ hc3, const float* __restrict__ h4,
                                                 const float* __restrict__ c1w, const float* __restrict__ c1b,
                                                 const float* __restrict__ c2w, const float* __restrict__ c2b,
                                                 const float* __restrict__ ow, const float* __restrict__ ob,
                                                 float* __restrict__ out) {
    __shared__ unsigned int svals[N];  // sortable key-high
    __shared__ float fvals[N];         // original h4
    __shared__ int hist[2048];
    __shared__ int canA[N], canB[N];
    __shared__ int winners[32];
    __shared__ int wsum[8];
    __shared__ int st_need, st_ncand, st_tb, st_cab, st_nwin;
    __shared__ int topk_s[K];
    __shared__ float pooled[K][TOT];
    __shared__ float c1[16][K];
    __shared__ float mp[16][16];
    __shared__ float dense[352];
    __shared__ float part[4][128];

    int g = blockIdx.x, t = threadIdx.x;
    int gbase = g * N;
    int lane = t & 63, w = t >> 6;

    for (int v = t; v < N; v += 512) {
        float f = h4[gbase + v];
        fvals[v] = f;
        unsigned int b = __float_as_uint(f);
        svals[v] = (b & 0x80000000u) ? ~b : (b | 0x80000000u);
    }
    if (t == 0) { st_need = K; st_nwin = 0; }

    auto mkkey = [&](int idx) {
        return ((unsigned long long)svals[idx] << 31) | (unsigned int)(0x7FFFFFFF - idx);
    };

    const int SHIFTS[6] = {52, 41, 30, 19, 8, 0};
    int curN = N;
    int src = 0; // 0: implicit [0,N), 1: canA, 2: canB
    for (int pass = 0; pass < 6; ++pass) {
        int shift = SHIFTS[pass];
        int mask = (pass == 5) ? 0xFF : 0x7FF;
        for (int i = t; i < 2048; i += 512) hist[i] = 0;
        if (t == 0) st_ncand = 0;
        __syncthreads();
        for (int i = t; i < curN; i += 512) {
            int idx = (src == 0) ? i : (src == 1 ? canA[i] : canB[i]);
            int d = (int)((mkkey(idx) >> shift) & mask);
            atomicAdd(&hist[d], 1);
        }
        __syncthreads();
        int need = st_need;
        // reverse-cumulative scan: thread t owns top-down positions 4t..4t+3
        int c[4];
        int s = 0;
#pragma unroll
        for (int u = 0; u < 4; ++u) { c[u] = hist[2047 - (4 * t + u)]; s += c[u]; }
        int x = s;
#pragma unroll
        for (int m = 1; m < 64; m <<= 1) {
            int y = __shfl_up(x, m, 64);
            if (lane >= m) x += y;
        }
        if (lane == 63) wsum[w] = x;
        __syncthreads();
        int woff = 0;
        for (int ww = 0; ww < w; ++ww) woff += wsum[ww];
        int A = woff + x - s; // count in buckets strictly above this thread's chunk
#pragma unroll
        for (int u = 0; u < 4; ++u) {
            if (A < need && need <= A + c[u]) { st_tb = 2047 - (4 * t + u); st_cab = A; }
            A += c[u];
        }
        __syncthreads();
        int tb = st_tb, cab = st_cab;
        int* dst = (src == 1) ? canB : canA;
        for (int i = t; i < curN; i += 512) {
            int idx = (src == 0) ? i : (src == 1 ? canA[i] : canB[i]);
            int d = (int)((mkkey(idx) >> shift) & mask);
            if (d > tb) {
                int p = atomicAdd(&st_nwin, 1);
                winners[p] = idx;
            } else if (d == tb) {
                int p = atomicAdd(&st_ncand, 1);
                dst[p] = idx;
            }
        }
        __syncthreads();
        int ncand = st_ncand;
        need -= cab;
        if (t == 0) st_need = need;
        if (ncand == need) {
            int base = st_nwin;
            for (int i = t; i < ncand; i += 512) winners[base + i] = dst[i];
            __syncthreads();
            break;
        }
        curN = ncand;
        src = (src == 1) ? 2 : 1;
        __syncthreads();
    }

    // exact ordering: bitonic sort of the 30 winner keys on wave 0
    if (t < 64) {
        unsigned long long key = (t < K) ? mkkey(winners[t]) : 0ull;
        unsigned long long kk = ~key; // ascending(~key) == descending(key)
#pragma unroll
        for (int k = 2; k <= 64; k <<= 1) {
#pragma unroll
            for (int j = k >> 1; j > 0; j >>= 1) {
                unsigned long long o = __shfl_xor(kk, j, 64);
                bool keepMin = ((t & j) == 0) == ((t & k) == 0);
                kk = keepMin ? (kk < o ? kk : o) : (kk > o ? kk : o);
            }
        }
        key = ~kk;
        if (t < K) topk_s[t] = 0x7FFFFFFF - (int)(unsigned int)(key & 0x7FFFFFFFu);
    }
    __syncthreads();

    for (int i = t; i < K * TOT; i += 512) {
        int k = i / TOT, d = i % TOT;
        int vloc = topk_s[k];
        int gi = gbase + vloc;
        float val = (d < 32) ? hc1[(size_t)gi * 32 + d]
                  : (d < 64) ? hc2[(size_t)gi * 32 + d - 32]
                  : (d < 96) ? hc3[(size_t)gi * 32 + d - 64]
                             : fvals[vloc];
        pooled[k][d] = val;
    }
    __syncthreads();
    for (int i = t; i < 16 * K; i += 512) {
        int o = i / K, k = i % K;
        float s = c1b[o];
        for (int d = 0; d < TOT; ++d) s += pooled[k][d] * c1w[o * TOT + d];
        c1[o][k] = fmaxf(s, 0.f);
    }
    __syncthreads();
    for (int i = t; i < 16 * 15; i += 512) {
        int o = i / 15, p = i % 15;
        mp[o][p] = fmaxf(c1[o][2 * p], c1[o][2 * p + 1]);
    }
    __syncthreads();
    for (int i = t; i < 352; i += 512) {
        int o = i / 11, p = i % 11;
        float s = c2b[o];
#pragma unroll
        for (int ci = 0; ci < 16; ++ci)
#pragma unroll
            for (int tt = 0; tt < 5; ++tt)
                s += mp[ci][p + tt] * c2w[(o * 16 + ci) * 5 + tt];
        dense[i] = fmaxf(s, 0.f);
    }
    __syncthreads();
    {
        int o = t & 127, q = t >> 7; // 4 partials of 88 terms each
        float s = 0.f;
        for (int m = q * 88; m < (q + 1) * 88; ++m) s += dense[m] * ow[m * 128 + o];
        part[q][o] = s;
    }
    __syncthreads();
    if (t < 128) {
        float s = (part[0][t] + part[1][t]) + (part[2][t] + part[3][t]) + ob[t];
        out[g * 128 + t] = fmaxf(s, 0.f);
    }
}

extern "C" void kernel_launch(void* const* d_in, const int* in_sizes, int n_in,
                              void* d_out, int out_size, void* d_ws, size_t ws_size,
                              hipStream_t stream) {
    const float* node_feat = (const float*)d_in[0];
    const int* esrc = (const int*)d_in[1];
    const int* edst = (const int*)d_in[2];
    const float* W1 = (const float*)d_in[3];
    const float* b1 = (const float*)d_in[4];
    const float* W2 = (const float*)d_in[5];
    const float* b2 = (const float*)d_in[6];
    const float* W3 = (const float*)d_in[7];
    const float* b3 = (const float*)d_in[8];
    const float* W4 = (const float*)d_in[9];
    const float* b4 = (const float*)d_in[10];
    const float* c1w = (const float*)d_in[11];
    const float* c1b = (const float*)d_in[12];
    const float* c2w = (const float*)d_in[13];
    const float* c2b = (const float*)d_in[14];
    const float* ow = (const float*)d_in[15];
    const float* ob = (const float*)d_in[16];

    char* ws = (char*)d_ws;
    size_t off = 0;
    auto alloc = [&](size_t bytes) {
        size_t r = off;
        off += (bytes + 255) & ~(size_t)255;
        return r;
    };
    int* deg_i = (int*)(ws + alloc((size_t)NT * 4));
    int* rowst = (int*)(ws + alloc((size_t)NT * 4));
    float* degf = (float*)(ws + alloc((size_t)NT * 4));
    int* csr = (int*)(ws + alloc((size_t)E_TOT * 4));
    float* tA = (float*)(ws + alloc((size_t)NT * 32 * 4));
    float* tB = (float*)(ws + alloc((size_t)NT * 32 * 4));
    float* hc1 = (float*)(ws + alloc((size_t)NT * 32 * 4));
    float* hc2 = (float*)(ws + alloc((size_t)NT * 32 * 4));
    float* hc3 = (float*)(ws + alloc((size_t)NT * 32 * 4));
    float* t4 = (float*)(ws + alloc((size_t)NT * 4));
    float* h4 = (float*)(ws + alloc((size_t)NT * 4));

    build_csr<<<B, 1024, 0, stream>>>(esrc, edst, csr, rowst, deg_i, degf);

    gemm_t<F_INN><<<NT / 128, 256, 0, stream>>>(node_feat, W1, tA);
    agg_f<32><<<8 * NB_G * 8, 256, 0, stream>>>(tA, csr, rowst, deg_i, degf, b1, W2, hc1, tB);
    agg_f<32><<<8 * NB_G * 8, 256, 0, stream>>>(tB, csr, rowst, deg_i, degf, b2, W3, hc2, tA);
    agg_f<1><<<8 * NB_G * 8, 256, 0, stream>>>(tA, csr, rowst, deg_i, degf, b3, W4, hc3, t4);
    agg1f<<<(NT + 255) / 256, 256, 0, stream>>>(t4, csr, rowst, deg_i, degf, b4, h4);

    sort_head<<<B, 512, 0, stream>>>(hc1, hc2, hc3, h4, c1w, c1b, c2w, c2b, ow, ob, (float*)d_out);
}

// Round 9
// 137.434 us; speedup vs baseline: 3.1047x; 1.2361x over previous
//
#include <hip/hip_runtime.h>

constexpr int B = 64, N = 1500, NT = B * N;
constexpr int E_PER = 24000, E_TOT = B * E_PER;
constexpr int E_PAD = 28512; // per-graph CSR slice, rows padded to 4 (24000 + 3*1500 = 28500, rounded up)
constexpr int F_INN = 128, K = 30, TOT = 97;
constexpr int NB_G = 47; // blocks per graph in agg_f (47*32 >= 1500)

// ---------------- Fused CSR build: one block per graph, padded CSR in LDS ------
__global__ __launch_bounds__(1024) void build_csr(const int* __restrict__ src, const int* __restrict__ dst,
                                                  int* __restrict__ csr, int* __restrict__ rowst,
                                                  int* __restrict__ degi, float* __restrict__ degf) {
    __shared__ int hist[N];        // counts -> cursors
    __shared__ int csr_l[E_PAD];   // ~114 KB padded CSR slice
    __shared__ int wsum[4];
    int g = blockIdx.x, t = threadIdx.x;
    int gbase = g * N;
    const int* dstg = dst + (size_t)g * E_PER;
    const int* srcg = src + (size_t)g * E_PER;

    for (int i = t; i < N; i += 1024) hist[i] = 0;
    for (int i = t; i < E_PAD; i += 1024) csr_l[i] = NT; // sentinel -> zero row of t
    __syncthreads();
    for (int e = t; e < E_PER; e += 1024)
        atomicAdd(&hist[dstg[e] - gbase], 1);
    __syncthreads();

    // prefix scan over PADDED counts (threads 0..255, 6 values each)
    int local[6];
    int sum = 0, x = 0;
    if (t < 256) {
#pragma unroll
        for (int i = 0; i < 6; ++i) {
            int v = t * 6 + i;
            int d = (v < N) ? hist[v] : 0;
            local[i] = d;
            sum += (d + 3) & ~3;
        }
        x = sum;
        int lane = t & 63;
#pragma unroll
        for (int m = 1; m < 64; m <<= 1) {
            int y = __shfl_up(x, m, 64);
            if (lane >= m) x += y;
        }
        if (lane == 63) wsum[t >> 6] = x;
    }
    __syncthreads();
    if (t < 256) {
        int woff = 0;
        int wv = t >> 6;
        for (int w = 0; w < wv; ++w) woff += wsum[w];
        int run = x - sum + woff; // exclusive prefix (padded) of this thread's chunk
#pragma unroll
        for (int i = 0; i < 6; ++i) {
            int v = t * 6 + i;
            if (v < N) {
                rowst[gbase + v] = g * E_PAD + run;
                degi[gbase + v] = local[i];
                degf[gbase + v] = (float)(local[i] + 1);
                hist[v] = run;
                run += (local[i] + 3) & ~3;
            }
        }
    }
    __syncthreads();
    for (int e = t; e < E_PER; e += 1024) {
        int d = dstg[e] - gbase;
        int pos = atomicAdd(&hist[d], 1);
        csr_l[pos] = srcg[e];
    }
    __syncthreads();
    for (int i = t; i < E_PAD; i += 1024)
        csr[(size_t)g * E_PAD + i] = csr_l[i];
}

// ---------------- Tiled GEMM: t[NT,32] = h[NT,128] @ W[128,32] ----------------
template <int KDIM>
__global__ __launch_bounds__(256) void gemm_t(const float* __restrict__ h,
                                              const float* __restrict__ W,
                                              float* __restrict__ t) {
    __shared__ float hs[32][128];
    __shared__ float Ws[32][32];
    int tid = threadIdx.x;
    int wv = tid >> 6, lane = tid & 63;
    int v0 = blockIdx.x * 128;
    int og = wv * 8;
    float acc[2][8];
#pragma unroll
    for (int i = 0; i < 2; ++i)
#pragma unroll
        for (int j = 0; j < 8; ++j) acc[i][j] = 0.f;

    for (int kc = 0; kc < KDIM; kc += 32) {
        __syncthreads();
        {
            int n = tid >> 1, kh = (tid & 1) * 16;
            const float* hp = h + (size_t)(v0 + n) * KDIM + kc + kh;
            const float4* hp4 = reinterpret_cast<const float4*>(hp);
            float4 a = hp4[0], b = hp4[1], c = hp4[2], d = hp4[3];
            hs[kh + 0][n] = a.x;  hs[kh + 1][n] = a.y;  hs[kh + 2][n] = a.z;  hs[kh + 3][n] = a.w;
            hs[kh + 4][n] = b.x;  hs[kh + 5][n] = b.y;  hs[kh + 6][n] = b.z;  hs[kh + 7][n] = b.w;
            hs[kh + 8][n] = c.x;  hs[kh + 9][n] = c.y;  hs[kh + 10][n] = c.z; hs[kh + 11][n] = c.w;
            hs[kh + 12][n] = d.x; hs[kh + 13][n] = d.y; hs[kh + 14][n] = d.z; hs[kh + 15][n] = d.w;
        }
        {
            int r = tid >> 3, c4 = (tid & 7) * 4;
            float4 w = *reinterpret_cast<const float4*>(W + (size_t)(kc + r) * 32 + c4);
            *reinterpret_cast<float4*>(&Ws[r][c4]) = w;
        }
        __syncthreads();
#pragma unroll
        for (int k = 0; k < 32; ++k) {
            float2 hv = *reinterpret_cast<const float2*>(&hs[k][2 * lane]);
            float4 w0 = *reinterpret_cast<const float4*>(&Ws[k][og]);
            float4 w1 = *reinterpret_cast<const float4*>(&Ws[k][og + 4]);
            acc[0][0] += hv.x * w0.x; acc[0][1] += hv.x * w0.y; acc[0][2] += hv.x * w0.z; acc[0][3] += hv.x * w0.w;
            acc[0][4] += hv.x * w1.x; acc[0][5] += hv.x * w1.y; acc[0][6] += hv.x * w1.z; acc[0][7] += hv.x * w1.w;
            acc[1][0] += hv.y * w0.x; acc[1][1] += hv.y * w0.y; acc[1][2] += hv.y * w0.z; acc[1][3] += hv.y * w0.w;
            acc[1][4] += hv.y * w1.x; acc[1][5] += hv.y * w1.y; acc[1][6] += hv.y * w1.z; acc[1][7] += hv.y * w1.w;
        }
    }
#pragma unroll
    for (int i = 0; i < 2; ++i) {
        float* op = t + (size_t)(v0 + 2 * lane + i) * 32 + og;
        float4 r0 = {acc[i][0], acc[i][1], acc[i][2], acc[i][3]};
        float4 r1 = {acc[i][4], acc[i][5], acc[i][6], acc[i][7]};
        reinterpret_cast<float4*>(op)[0] = r0;
        reinterpret_cast<float4*>(op)[1] = r1;
    }
}

// ---- Aggregate (float4 lanes, 8 lanes/node) + fused transform; XCD swizzle ----
// t has NT+1 rows; row NT is zero (sentinel for CSR padding).
template <int FUSE>
__global__ __launch_bounds__(256) void agg_f(const float* __restrict__ t,
                                             const int* __restrict__ csr, const int* __restrict__ rowst,
                                             const int* __restrict__ degi, const float* __restrict__ degf,
                                             const float* __restrict__ bias, const float* __restrict__ Wn,
                                             float* __restrict__ hout, float* __restrict__ tn) {
    __shared__ float Ws[1024];
    __shared__ float outs[32][32];
    if (FUSE == 32) {
        for (int i = threadIdx.x; i < 1024; i += 256) Ws[i] = Wn[i];
    }
    int bid = blockIdx.x;
    int xcd = bid & 7, j = bid >> 3;
    int g = xcd + 8 * (j / NB_G);
    int nb = j % NB_G;
    int nl = threadIdx.x >> 3; // node within block [0,32)
    int f4 = threadIdx.x & 7;  // float4 slot [0,8)
    int vl = nb * 32 + nl;
    bool valid = vl < N;
    int v = g * N + vl;
    const float4* t4v = reinterpret_cast<const float4*>(t);
    float4 out = {0.f, 0.f, 0.f, 0.f};
    if (valid) {
        float4 acc = t4v[(unsigned)(v * 8 + f4)];
        int e0 = rowst[v];
        int dc = degi[v];
        int pc = (dc + 3) & ~3;
        float4 s1 = {0.f, 0.f, 0.f, 0.f}, s2 = {0.f, 0.f, 0.f, 0.f};
        for (int e = 0; e < pc; e += 4) {
            int4 s4 = *reinterpret_cast<const int4*>(csr + e0 + e);
            float4 x0 = t4v[(unsigned)(s4.x * 8 + f4)];
            float4 x1 = t4v[(unsigned)(s4.y * 8 + f4)];
            float4 x2 = t4v[(unsigned)(s4.z * 8 + f4)];
            float4 x3 = t4v[(unsigned)(s4.w * 8 + f4)];
            s1.x += x0.x + x1.x; s1.y += x0.y + x1.y; s1.z += x0.z + x1.z; s1.w += x0.w + x1.w;
            s2.x += x2.x + x3.x; s2.y += x2.y + x3.y; s2.z += x2.z + x3.z; s2.w += x2.w + x3.w;
        }
        acc.x += s1.x + s2.x; acc.y += s1.y + s2.y; acc.z += s1.z + s2.z; acc.w += s1.w + s2.w;
        float4 bv = *reinterpret_cast<const float4*>(bias + f4 * 4);
        float inv = 1.0f / degf[v];
        out.x = tanhf((acc.x + bv.x) * inv);
        out.y = tanhf((acc.y + bv.y) * inv);
        out.z = tanhf((acc.z + bv.z) * inv);
        out.w = tanhf((acc.w + bv.w) * inv);
        reinterpret_cast<float4*>(hout)[(unsigned)(v * 8 + f4)] = out;
    }
    if (FUSE == 32) {
        *reinterpret_cast<float4*>(&outs[nl][f4 * 4]) = out;
        __syncthreads();
        if (valid) {
            float4 s = {0.f, 0.f, 0.f, 0.f};
#pragma unroll
            for (int ff = 0; ff < 32; ++ff) {
                float h = outs[nl][ff];
                float4 wr = *reinterpret_cast<const float4*>(&Ws[ff * 32 + f4 * 4]);
                s.x += h * wr.x; s.y += h * wr.y; s.z += h * wr.z; s.w += h * wr.w;
            }
            reinterpret_cast<float4*>(tn)[(unsigned)(v * 8 + f4)] = s;
        }
    } else if (valid) {
        float4 w4 = *reinterpret_cast<const float4*>(Wn + f4 * 4);
        float p = out.x * w4.x + out.y * w4.y + out.z * w4.z + out.w * w4.w;
        p += __shfl_xor(p, 4, 64);
        p += __shfl_xor(p, 2, 64);
        p += __shfl_xor(p, 1, 64);
        if (f4 == 0) tn[v] = p;
    }
}

// ---------------- Layer-4 aggregate: scalar gather (padded rows) ----------------
__global__ __launch_bounds__(256) void agg1f(const float* __restrict__ t4,
                                             const int* __restrict__ csr, const int* __restrict__ rowst,
                                             const int* __restrict__ degi, const float* __restrict__ degf,
                                             const float* __restrict__ b4, float* __restrict__ h4) {
    int v = blockIdx.x * 256 + threadIdx.x;
    if (v >= NT) return;
    float acc = t4[v];
    int e0 = rowst[v], dc = degi[v];
    int pc = (dc + 3) & ~3;
    float a0 = 0.f, a1 = 0.f, a2 = 0.f, a3 = 0.f;
    for (int e = 0; e < pc; e += 4) {
        int4 s4 = *reinterpret_cast<const int4*>(csr + e0 + e);
        a0 += t4[s4.x];
        a1 += t4[s4.y];
        a2 += t4[s4.z];
        a3 += t4[s4.w];
    }
    acc += (a0 + a1) + (a2 + a3);
    h4[v] = tanhf((acc + b4[0]) / degf[v]);
}

// -------- Fused sortpool (radix top-K) + head: one 512-thread block/graph -----
__global__ __launch_bounds__(512) void sort_head(const float* __restrict__ hc1, const float* __restrict__ hc2,
                                                 const float* __restrict__ hc3, const float* __restrict__ h4,
                                                 const float* __restrict__ c1w, const float* __restrict__ c1b,
                                                 const float* __restrict__ c2w, const float* __restrict__ c2b,
                                                 const float* __restrict__ ow, const float* __restrict__ ob,
                                                 float* __restrict__ out) {
    __shared__ unsigned int svals[N];  // sortable key-high
    __shared__ float fvals[N];         // original h4
    __shared__ int hist[2048];
    __shared__ int canA[N], canB[N];
    __shared__ int winners[32];
    __shared__ int wsum[8];
    __shared__ int st_need, st_ncand, st_tb, st_cab, st_nwin;
    __shared__ int topk_s[K];
    __shared__ float pooled[K][TOT];
    __shared__ float c1[16][K];
    __shared__ float mp[16][16];
    __shared__ float dense[352];
    __shared__ float part[4][128];

    int g = blockIdx.x, t = threadIdx.x;
    int gbase = g * N;
    int lane = t & 63, w = t >> 6;

    for (int v = t; v < N; v += 512) {
        float f = h4[gbase + v];
        fvals[v] = f;
        unsigned int b = __float_as_uint(f);
        svals[v] = (b & 0x80000000u) ? ~b : (b | 0x80000000u);
    }
    if (t == 0) { st_need = K; st_nwin = 0; }

    auto mkkey = [&](int idx) {
        return ((unsigned long long)svals[idx] << 31) | (unsigned int)(0x7FFFFFFF - idx);
    };

    const int SHIFTS[6] = {52, 41, 30, 19, 8, 0};
    int curN = N;
    int src = 0; // 0: implicit [0,N), 1: canA, 2: canB
    for (int pass = 0; pass < 6; ++pass) {
        int shift = SHIFTS[pass];
        int mask = (pass == 5) ? 0xFF : 0x7FF;
        for (int i = t; i < 2048; i += 512) hist[i] = 0;
        if (t == 0) st_ncand = 0;
        __syncthreads();
        for (int i = t; i < curN; i += 512) {
            int idx = (src == 0) ? i : (src == 1 ? canA[i] : canB[i]);
            int d = (int)((mkkey(idx) >> shift) & mask);
            atomicAdd(&hist[d], 1);
        }
        __syncthreads();
        int need = st_need;
        int c[4];
        int s = 0;
#pragma unroll
        for (int u = 0; u < 4; ++u) { c[u] = hist[2047 - (4 * t + u)]; s += c[u]; }
        int x = s;
#pragma unroll
        for (int m = 1; m < 64; m <<= 1) {
            int y = __shfl_up(x, m, 64);
            if (lane >= m) x += y;
        }
        if (lane == 63) wsum[w] = x;
        __syncthreads();
        int woff = 0;
        for (int ww = 0; ww < w; ++ww) woff += wsum[ww];
        int A = woff + x - s;
#pragma unroll
        for (int u = 0; u < 4; ++u) {
            if (A < need && need <= A + c[u]) { st_tb = 2047 - (4 * t + u); st_cab = A; }
            A += c[u];
        }
        __syncthreads();
        int tb = st_tb, cab = st_cab;
        int* dst = (src == 1) ? canB : canA;
        for (int i = t; i < curN; i += 512) {
            int idx = (src == 0) ? i : (src == 1 ? canA[i] : canB[i]);
            int d = (int)((mkkey(idx) >> shift) & mask);
            if (d > tb) {
                int p = atomicAdd(&st_nwin, 1);
                winners[p] = idx;
            } else if (d == tb) {
                int p = atomicAdd(&st_ncand, 1);
                dst[p] = idx;
            }
        }
        __syncthreads();
        int ncand = st_ncand;
        need -= cab;
        if (t == 0) st_need = need;
        if (ncand == need) {
            int base = st_nwin;
            for (int i = t; i < ncand; i += 512) winners[base + i] = dst[i];
            __syncthreads();
            break;
        }
        curN = ncand;
        src = (src == 1) ? 2 : 1;
        __syncthreads();
    }

    // exact ordering: bitonic sort of the 30 winner keys on wave 0
    if (t < 64) {
        unsigned long long key = (t < K) ? mkkey(winners[t]) : 0ull;
        unsigned long long kk = ~key;
#pragma unroll
        for (int k = 2; k <= 64; k <<= 1) {
#pragma unroll
            for (int j = k >> 1; j > 0; j >>= 1) {
                unsigned long long o = __shfl_xor(kk, j, 64);
                bool keepMin = ((t & j) == 0) == ((t & k) == 0);
                kk = keepMin ? (kk < o ? kk : o) : (kk > o ? kk : o);
            }
        }
        key = ~kk;
        if (t < K) topk_s[t] = 0x7FFFFFFF - (int)(unsigned int)(key & 0x7FFFFFFFu);
    }
    __syncthreads();

    for (int i = t; i < K * TOT; i += 512) {
        int k = i / TOT, d = i % TOT;
        int vloc = topk_s[k];
        int gi = gbase + vloc;
        float val = (d < 32) ? hc1[(size_t)gi * 32 + d]
                  : (d < 64) ? hc2[(size_t)gi * 32 + d - 32]
                  : (d < 96) ? hc3[(size_t)gi * 32 + d - 64]
                             : fvals[vloc];
        pooled[k][d] = val;
    }
    __syncthreads();
    for (int i = t; i < 16 * K; i += 512) {
        int o = i / K, k = i % K;
        float s = c1b[o];
        for (int d = 0; d < TOT; ++d) s += pooled[k][d] * c1w[o * TOT + d];
        c1[o][k] = fmaxf(s, 0.f);
    }
    __syncthreads();
    for (int i = t; i < 16 * 15; i += 512) {
        int o = i / 15, p = i % 15;
        mp[o][p] = fmaxf(c1[o][2 * p], c1[o][2 * p + 1]);
    }
    __syncthreads();
    for (int i = t; i < 352; i += 512) {
        int o = i / 11, p = i % 11;
        float s = c2b[o];
#pragma unroll
        for (int ci = 0; ci < 16; ++ci)
#pragma unroll
            for (int tt = 0; tt < 5; ++tt)
                s += mp[ci][p + tt] * c2w[(o * 16 + ci) * 5 + tt];
        dense[i] = fmaxf(s, 0.f);
    }
    __syncthreads();
    {
        int o = t & 127, q = t >> 7;
        float s = 0.f;
        for (int m = q * 88; m < (q + 1) * 88; ++m) s += dense[m] * ow[m * 128 + o];
        part[q][o] = s;
    }
    __syncthreads();
    if (t < 128) {
        float s = (part[0][t] + part[1][t]) + (part[2][t] + part[3][t]) + ob[t];
        out[g * 128 + t] = fmaxf(s, 0.f);
    }
}

extern "C" void kernel_launch(void* const* d_in, const int* in_sizes, int n_in,
                              void* d_out, int out_size, void* d_ws, size_t ws_size,
                              hipStream_t stream) {
    const float* node_feat = (const float*)d_in[0];
    const int* esrc = (const int*)d_in[1];
    const int* edst = (const int*)d_in[2];
    const float* W1 = (const float*)d_in[3];
    const float* b1 = (const float*)d_in[4];
    const float* W2 = (const float*)d_in[5];
    const float* b2 = (const float*)d_in[6];
    const float* W3 = (const float*)d_in[7];
    const float* b3 = (const float*)d_in[8];
    const float* W4 = (const float*)d_in[9];
    const float* b4 = (const float*)d_in[10];
    const float* c1w = (const float*)d_in[11];
    const float* c1b = (const float*)d_in[12];
    const float* c2w = (const float*)d_in[13];
    const float* c2b = (const float*)d_in[14];
    const float* ow = (const float*)d_in[15];
    const float* ob = (const float*)d_in[16];

    char* ws = (char*)d_ws;
    size_t off = 0;
    auto alloc = [&](size_t bytes) {
        size_t r = off;
        off += (bytes + 255) & ~(size_t)255;
        return r;
    };
    int* deg_i = (int*)(ws + alloc((size_t)NT * 4));
    int* rowst = (int*)(ws + alloc((size_t)NT * 4));
    float* degf = (float*)(ws + alloc((size_t)NT * 4));
    int* csr = (int*)(ws + alloc((size_t)B * E_PAD * 4));
    float* tA = (float*)(ws + alloc((size_t)(NT + 1) * 32 * 4));  // +1 zero sentinel row
    float* tB = (float*)(ws + alloc((size_t)(NT + 1) * 32 * 4));
    float* hc1 = (float*)(ws + alloc((size_t)NT * 32 * 4));
    float* hc2 = (float*)(ws + alloc((size_t)NT * 32 * 4));
    float* hc3 = (float*)(ws + alloc((size_t)NT * 32 * 4));
    float* t4 = (float*)(ws + alloc((size_t)(NT + 1) * 4));
    float* h4 = (float*)(ws + alloc((size_t)NT * 4));

    // zero the sentinel rows (CSR pads gather these; must contribute +0)
    hipMemsetAsync(tA + (size_t)NT * 32, 0, 32 * 4, stream);
    hipMemsetAsync(tB + (size_t)NT * 32, 0, 32 * 4, stream);
    hipMemsetAsync(t4 + NT, 0, 4, stream);

    build_csr<<<B, 1024, 0, stream>>>(esrc, edst, csr, rowst, deg_i, degf);

    gemm_t<F_INN><<<NT / 128, 256, 0, stream>>>(node_feat, W1, tA);
    agg_f<32><<<8 * NB_G * 8, 256, 0, stream>>>(tA, csr, rowst, deg_i, degf, b1, W2, hc1, tB);
    agg_f<32><<<8 * NB_G * 8, 256, 0, stream>>>(tB, csr, rowst, deg_i, degf, b2, W3, hc2, tA);
    agg_f<1><<<8 * NB_G * 8, 256, 0, stream>>>(tA, csr, rowst, deg_i, degf, b3, W4, hc3, t4);
    agg1f<<<(NT + 255) / 256, 256, 0, stream>>>(t4, csr, rowst, deg_i, degf, b4, h4);

    sort_head<<<B, 512, 0, stream>>>(hc1, hc2, hc3, h4, c1w, c1b, c2w, c2b, ow, ob, (float*)d_out);
}

// Round 10
// 127.667 us; speedup vs baseline: 3.3423x; 1.0765x over previous
//
#include <hip/hip_runtime.h>

constexpr int B = 64, N = 1500, NT = B * N;
constexpr int E_PER = 24000, E_TOT = B * E_PER;
constexpr int E_PAD = 28512; // per-graph CSR slice, rows padded to 4 (24000 + 3*1500 = 28500, rounded up)
constexpr int F_INN = 128, K = 30, TOT = 97;
constexpr int NB_G = 47; // blocks per graph in agg_f (47*32 >= 1500)

// ---------------- Fused CSR build: one block per graph, padded CSR in LDS ------
// Also zeroes the sentinel rows of tA/tB/t4 (row NT) so padded CSR entries
// gather +0.0 — no hipMemsetAsync (runtime fill kernels cost ~39 us each).
__global__ __launch_bounds__(1024) void build_csr(const int* __restrict__ src, const int* __restrict__ dst,
                                                  int* __restrict__ csr, int* __restrict__ rowst,
                                                  int* __restrict__ degi, float* __restrict__ degf,
                                                  float* __restrict__ tA, float* __restrict__ tB,
                                                  float* __restrict__ t4) {
    __shared__ int hist[N];        // counts -> cursors
    __shared__ int csr_l[E_PAD];   // ~114 KB padded CSR slice
    __shared__ int wsum[4];
    int g = blockIdx.x, t = threadIdx.x;
    int gbase = g * N;
    const int* dstg = dst + (size_t)g * E_PER;
    const int* srcg = src + (size_t)g * E_PER;

    if (g == 0) { // zero sentinel rows (row NT)
        if (t < 32) tA[(size_t)NT * 32 + t] = 0.f;
        else if (t < 64) tB[(size_t)NT * 32 + (t - 32)] = 0.f;
        else if (t == 64) t4[NT] = 0.f;
    }

    for (int i = t; i < N; i += 1024) hist[i] = 0;
    for (int i = t; i < E_PAD; i += 1024) csr_l[i] = NT; // sentinel -> zero row of t
    __syncthreads();
    for (int e = t; e < E_PER; e += 1024)
        atomicAdd(&hist[dstg[e] - gbase], 1);
    __syncthreads();

    // prefix scan over PADDED counts (threads 0..255, 6 values each)
    int local[6];
    int sum = 0, x = 0;
    if (t < 256) {
#pragma unroll
        for (int i = 0; i < 6; ++i) {
            int v = t * 6 + i;
            int d = (v < N) ? hist[v] : 0;
            local[i] = d;
            sum += (d + 3) & ~3;
        }
        x = sum;
        int lane = t & 63;
#pragma unroll
        for (int m = 1; m < 64; m <<= 1) {
            int y = __shfl_up(x, m, 64);
            if (lane >= m) x += y;
        }
        if (lane == 63) wsum[t >> 6] = x;
    }
    __syncthreads();
    if (t < 256) {
        int woff = 0;
        int wv = t >> 6;
        for (int w = 0; w < wv; ++w) woff += wsum[w];
        int run = x - sum + woff; // exclusive prefix (padded) of this thread's chunk
#pragma unroll
        for (int i = 0; i < 6; ++i) {
            int v = t * 6 + i;
            if (v < N) {
                rowst[gbase + v] = g * E_PAD + run;
                degi[gbase + v] = local[i];
                degf[gbase + v] = (float)(local[i] + 1);
                hist[v] = run;
                run += (local[i] + 3) & ~3;
            }
        }
    }
    __syncthreads();
    for (int e = t; e < E_PER; e += 1024) {
        int d = dstg[e] - gbase;
        int pos = atomicAdd(&hist[d], 1);
        csr_l[pos] = srcg[e];
    }
    __syncthreads();
    for (int i = t; i < E_PAD; i += 1024)
        csr[(size_t)g * E_PAD + i] = csr_l[i];
}

// ---------------- Tiled GEMM: t[NT,32] = h[NT,128] @ W[128,32] ----------------
template <int KDIM>
__global__ __launch_bounds__(256) void gemm_t(const float* __restrict__ h,
                                              const float* __restrict__ W,
                                              float* __restrict__ t) {
    __shared__ float hs[32][128];
    __shared__ float Ws[32][32];
    int tid = threadIdx.x;
    int wv = tid >> 6, lane = tid & 63;
    int v0 = blockIdx.x * 128;
    int og = wv * 8;
    float acc[2][8];
#pragma unroll
    for (int i = 0; i < 2; ++i)
#pragma unroll
        for (int j = 0; j < 8; ++j) acc[i][j] = 0.f;

    for (int kc = 0; kc < KDIM; kc += 32) {
        __syncthreads();
        {
            int n = tid >> 1, kh = (tid & 1) * 16;
            const float* hp = h + (size_t)(v0 + n) * KDIM + kc + kh;
            const float4* hp4 = reinterpret_cast<const float4*>(hp);
            float4 a = hp4[0], b = hp4[1], c = hp4[2], d = hp4[3];
            hs[kh + 0][n] = a.x;  hs[kh + 1][n] = a.y;  hs[kh + 2][n] = a.z;  hs[kh + 3][n] = a.w;
            hs[kh + 4][n] = b.x;  hs[kh + 5][n] = b.y;  hs[kh + 6][n] = b.z;  hs[kh + 7][n] = b.w;
            hs[kh + 8][n] = c.x;  hs[kh + 9][n] = c.y;  hs[kh + 10][n] = c.z; hs[kh + 11][n] = c.w;
            hs[kh + 12][n] = d.x; hs[kh + 13][n] = d.y; hs[kh + 14][n] = d.z; hs[kh + 15][n] = d.w;
        }
        {
            int r = tid >> 3, c4 = (tid & 7) * 4;
            float4 w = *reinterpret_cast<const float4*>(W + (size_t)(kc + r) * 32 + c4);
            *reinterpret_cast<float4*>(&Ws[r][c4]) = w;
        }
        __syncthreads();
#pragma unroll
        for (int k = 0; k < 32; ++k) {
            float2 hv = *reinterpret_cast<const float2*>(&hs[k][2 * lane]);
            float4 w0 = *reinterpret_cast<const float4*>(&Ws[k][og]);
            float4 w1 = *reinterpret_cast<const float4*>(&Ws[k][og + 4]);
            acc[0][0] += hv.x * w0.x; acc[0][1] += hv.x * w0.y; acc[0][2] += hv.x * w0.z; acc[0][3] += hv.x * w0.w;
            acc[0][4] += hv.x * w1.x; acc[0][5] += hv.x * w1.y; acc[0][6] += hv.x * w1.z; acc[0][7] += hv.x * w1.w;
            acc[1][0] += hv.y * w0.x; acc[1][1] += hv.y * w0.y; acc[1][2] += hv.y * w0.z; acc[1][3] += hv.y * w0.w;
            acc[1][4] += hv.y * w1.x; acc[1][5] += hv.y * w1.y; acc[1][6] += hv.y * w1.z; acc[1][7] += hv.y * w1.w;
        }
    }
#pragma unroll
    for (int i = 0; i < 2; ++i) {
        float* op = t + (size_t)(v0 + 2 * lane + i) * 32 + og;
        float4 r0 = {acc[i][0], acc[i][1], acc[i][2], acc[i][3]};
        float4 r1 = {acc[i][4], acc[i][5], acc[i][6], acc[i][7]};
        reinterpret_cast<float4*>(op)[0] = r0;
        reinterpret_cast<float4*>(op)[1] = r1;
    }
}

// ---- Aggregate (float4 lanes, 8 lanes/node) + fused transform; XCD swizzle ----
// t has NT+1 rows; row NT is zero (sentinel for CSR padding).
template <int FUSE>
__global__ __launch_bounds__(256) void agg_f(const float* __restrict__ t,
                                             const int* __restrict__ csr, const int* __restrict__ rowst,
                                             const int* __restrict__ degi, const float* __restrict__ degf,
                                             const float* __restrict__ bias, const float* __restrict__ Wn,
                                             float* __restrict__ hout, float* __restrict__ tn) {
    __shared__ float Ws[1024];
    __shared__ float outs[32][32];
    if (FUSE == 32) {
        for (int i = threadIdx.x; i < 1024; i += 256) Ws[i] = Wn[i];
    }
    int bid = blockIdx.x;
    int xcd = bid & 7, j = bid >> 3;
    int g = xcd + 8 * (j / NB_G);
    int nb = j % NB_G;
    int nl = threadIdx.x >> 3; // node within block [0,32)
    int f4 = threadIdx.x & 7;  // float4 slot [0,8)
    int vl = nb * 32 + nl;
    bool valid = vl < N;
    int v = g * N + vl;
    const float4* t4v = reinterpret_cast<const float4*>(t);
    float4 out = {0.f, 0.f, 0.f, 0.f};
    if (valid) {
        float4 acc = t4v[(unsigned)(v * 8 + f4)];
        int e0 = rowst[v];
        int dc = degi[v];
        int pc = (dc + 3) & ~3;
        float4 s1 = {0.f, 0.f, 0.f, 0.f}, s2 = {0.f, 0.f, 0.f, 0.f};
        for (int e = 0; e < pc; e += 4) {
            int4 s4 = *reinterpret_cast<const int4*>(csr + e0 + e);
            float4 x0 = t4v[(unsigned)(s4.x * 8 + f4)];
            float4 x1 = t4v[(unsigned)(s4.y * 8 + f4)];
            float4 x2 = t4v[(unsigned)(s4.z * 8 + f4)];
            float4 x3 = t4v[(unsigned)(s4.w * 8 + f4)];
            s1.x += x0.x + x1.x; s1.y += x0.y + x1.y; s1.z += x0.z + x1.z; s1.w += x0.w + x1.w;
            s2.x += x2.x + x3.x; s2.y += x2.y + x3.y; s2.z += x2.z + x3.z; s2.w += x2.w + x3.w;
        }
        acc.x += s1.x + s2.x; acc.y += s1.y + s2.y; acc.z += s1.z + s2.z; acc.w += s1.w + s2.w;
        float4 bv = *reinterpret_cast<const float4*>(bias + f4 * 4);
        float inv = 1.0f / degf[v];
        out.x = tanhf((acc.x + bv.x) * inv);
        out.y = tanhf((acc.y + bv.y) * inv);
        out.z = tanhf((acc.z + bv.z) * inv);
        out.w = tanhf((acc.w + bv.w) * inv);
        reinterpret_cast<float4*>(hout)[(unsigned)(v * 8 + f4)] = out;
    }
    if (FUSE == 32) {
        *reinterpret_cast<float4*>(&outs[nl][f4 * 4]) = out;
        __syncthreads();
        if (valid) {
            float4 s = {0.f, 0.f, 0.f, 0.f};
#pragma unroll
            for (int ff = 0; ff < 32; ++ff) {
                float h = outs[nl][ff];
                float4 wr = *reinterpret_cast<const float4*>(&Ws[ff * 32 + f4 * 4]);
                s.x += h * wr.x; s.y += h * wr.y; s.z += h * wr.z; s.w += h * wr.w;
            }
            reinterpret_cast<float4*>(tn)[(unsigned)(v * 8 + f4)] = s;
        }
    } else if (valid) {
        float4 w4 = *reinterpret_cast<const float4*>(Wn + f4 * 4);
        float p = out.x * w4.x + out.y * w4.y + out.z * w4.z + out.w * w4.w;
        p += __shfl_xor(p, 4, 64);
        p += __shfl_xor(p, 2, 64);
        p += __shfl_xor(p, 1, 64);
        if (f4 == 0) tn[v] = p;
    }
}

// ---------------- Layer-4 aggregate: scalar gather (padded rows) ----------------
__global__ __launch_bounds__(256) void agg1f(const float* __restrict__ t4,
                                             const int* __restrict__ csr, const int* __restrict__ rowst,
                                             const int* __restrict__ degi, const float* __restrict__ degf,
                                             const float* __restrict__ b4, float* __restrict__ h4) {
    int v = blockIdx.x * 256 + threadIdx.x;
    if (v >= NT) return;
    float acc = t4[v];
    int e0 = rowst[v], dc = degi[v];
    int pc = (dc + 3) & ~3;
    float a0 = 0.f, a1 = 0.f, a2 = 0.f, a3 = 0.f;
    for (int e = 0; e < pc; e += 4) {
        int4 s4 = *reinterpret_cast<const int4*>(csr + e0 + e);
        a0 += t4[s4.x];
        a1 += t4[s4.y];
        a2 += t4[s4.z];
        a3 += t4[s4.w];
    }
    acc += (a0 + a1) + (a2 + a3);
    h4[v] = tanhf((acc + b4[0]) / degf[v]);
}

// -------- Fused sortpool (radix top-K) + head: one 512-thread block/graph -----
__global__ __launch_bounds__(512) void sort_head(const float* __restrict__ hc1, const float* __restrict__ hc2,
                                                 const float* __restrict__ hc3, const float* __restrict__ h4,
                                                 const float* __restrict__ c1w, const float* __restrict__ c1b,
                                                 const float* __restrict__ c2w, const float* __restrict__ c2b,
                                                 const float* __restrict__ ow, const float* __restrict__ ob,
                                                 float* __restrict__ out) {
    __shared__ unsigned int svals[N];  // sortable key-high
    __shared__ float fvals[N];         // original h4
    __shared__ int hist[2048];
    __shared__ int canA[N], canB[N];
    __shared__ int winners[32];
    __shared__ int wsum[8];
    __shared__ int st_need, st_ncand, st_tb, st_cab, st_nwin;
    __shared__ int topk_s[K];
    __shared__ float pooled[K][TOT];
    __shared__ float c1[16][K];
    __shared__ float mp[16][16];
    __shared__ float dense[352];
    __shared__ float part[4][128];

    int g = blockIdx.x, t = threadIdx.x;
    int gbase = g * N;
    int lane = t & 63, w = t >> 6;

    for (int v = t; v < N; v += 512) {
        float f = h4[gbase + v];
        fvals[v] = f;
        unsigned int b = __float_as_uint(f);
        svals[v] = (b & 0x80000000u) ? ~b : (b | 0x80000000u);
    }
    if (t == 0) { st_need = K; st_nwin = 0; }

    auto mkkey = [&](int idx) {
        return ((unsigned long long)svals[idx] << 31) | (unsigned int)(0x7FFFFFFF - idx);
    };

    const int SHIFTS[6] = {52, 41, 30, 19, 8, 0};
    int curN = N;
    int src = 0; // 0: implicit [0,N), 1: canA, 2: canB
    for (int pass = 0; pass < 6; ++pass) {
        int shift = SHIFTS[pass];
        int mask = (pass == 5) ? 0xFF : 0x7FF;
        for (int i = t; i < 2048; i += 512) hist[i] = 0;
        if (t == 0) st_ncand = 0;
        __syncthreads();
        for (int i = t; i < curN; i += 512) {
            int idx = (src == 0) ? i : (src == 1 ? canA[i] : canB[i]);
            int d = (int)((mkkey(idx) >> shift) & mask);
            atomicAdd(&hist[d], 1);
        }
        __syncthreads();
        int need = st_need;
        int c[4];
        int s = 0;
#pragma unroll
        for (int u = 0; u < 4; ++u) { c[u] = hist[2047 - (4 * t + u)]; s += c[u]; }
        int x = s;
#pragma unroll
        for (int m = 1; m < 64; m <<= 1) {
            int y = __shfl_up(x, m, 64);
            if (lane >= m) x += y;
        }
        if (lane == 63) wsum[w] = x;
        __syncthreads();
        int woff = 0;
        for (int ww = 0; ww < w; ++ww) woff += wsum[ww];
        int A = woff + x - s;
#pragma unroll
        for (int u = 0; u < 4; ++u) {
            if (A < need && need <= A + c[u]) { st_tb = 2047 - (4 * t + u); st_cab = A; }
            A += c[u];
        }
        __syncthreads();
        int tb = st_tb, cab = st_cab;
        int* dst = (src == 1) ? canB : canA;
        for (int i = t; i < curN; i += 512) {
            int idx = (src == 0) ? i : (src == 1 ? canA[i] : canB[i]);
            int d = (int)((mkkey(idx) >> shift) & mask);
            if (d > tb) {
                int p = atomicAdd(&st_nwin, 1);
                winners[p] = idx;
            } else if (d == tb) {
                int p = atomicAdd(&st_ncand, 1);
                dst[p] = idx;
            }
        }
        __syncthreads();
        int ncand = st_ncand;
        need -= cab;
        if (t == 0) st_need = need;
        if (ncand == need) {
            int base = st_nwin;
            for (int i = t; i < ncand; i += 512) winners[base + i] = dst[i];
            __syncthreads();
            break;
        }
        curN = ncand;
        src = (src == 1) ? 2 : 1;
        __syncthreads();
    }

    // exact ordering: bitonic sort of the 30 winner keys on wave 0
    if (t < 64) {
        unsigned long long key = (t < K) ? mkkey(winners[t]) : 0ull;
        unsigned long long kk = ~key;
#pragma unroll
        for (int k = 2; k <= 64; k <<= 1) {
#pragma unroll
            for (int j = k >> 1; j > 0; j >>= 1) {
                unsigned long long o = __shfl_xor(kk, j, 64);
                bool keepMin = ((t & j) == 0) == ((t & k) == 0);
                kk = keepMin ? (kk < o ? kk : o) : (kk > o ? kk : o);
            }
        }
        key = ~kk;
        if (t < K) topk_s[t] = 0x7FFFFFFF - (int)(unsigned int)(key & 0x7FFFFFFFu);
    }
    __syncthreads();

    for (int i = t; i < K * TOT; i += 512) {
        int k = i / TOT, d = i % TOT;
        int vloc = topk_s[k];
        int gi = gbase + vloc;
        float val = (d < 32) ? hc1[(size_t)gi * 32 + d]
                  : (d < 64) ? hc2[(size_t)gi * 32 + d - 32]
                  : (d < 96) ? hc3[(size_t)gi * 32 + d - 64]
                             : fvals[vloc];
        pooled[k][d] = val;
    }
    __syncthreads();
    for (int i = t; i < 16 * K; i += 512) {
        int o = i / K, k = i % K;
        float s = c1b[o];
        for (int d = 0; d < TOT; ++d) s += pooled[k][d] * c1w[o * TOT + d];
        c1[o][k] = fmaxf(s, 0.f);
    }
    __syncthreads();
    for (int i = t; i < 16 * 15; i += 512) {
        int o = i / 15, p = i % 15;
        mp[o][p] = fmaxf(c1[o][2 * p], c1[o][2 * p + 1]);
    }
    __syncthreads();
    for (int i = t; i < 352; i += 512) {
        int o = i / 11, p = i % 11;
        float s = c2b[o];
#pragma unroll
        for (int ci = 0; ci < 16; ++ci)
#pragma unroll
            for (int tt = 0; tt < 5; ++tt)
                s += mp[ci][p + tt] * c2w[(o * 16 + ci) * 5 + tt];
        dense[i] = fmaxf(s, 0.f);
    }
    __syncthreads();
    {
        int o = t & 127, q = t >> 7;
        float s = 0.f;
        for (int m = q * 88; m < (q + 1) * 88; ++m) s += dense[m] * ow[m * 128 + o];
        part[q][o] = s;
    }
    __syncthreads();
    if (t < 128) {
        float s = (part[0][t] + part[1][t]) + (part[2][t] + part[3][t]) + ob[t];
        out[g * 128 + t] = fmaxf(s, 0.f);
    }
}

extern "C" void kernel_launch(void* const* d_in, const int* in_sizes, int n_in,
                              void* d_out, int out_size, void* d_ws, size_t ws_size,
                              hipStream_t stream) {
    const float* node_feat = (const float*)d_in[0];
    const int* esrc = (const int*)d_in[1];
    const int* edst = (const int*)d_in[2];
    const float* W1 = (const float*)d_in[3];
    const float* b1 = (const float*)d_in[4];
    const float* W2 = (const float*)d_in[5];
    const float* b2 = (const float*)d_in[6];
    const float* W3 = (const float*)d_in[7];
    const float* b3 = (const float*)d_in[8];
    const float* W4 = (const float*)d_in[9];
    const float* b4 = (const float*)d_in[10];
    const float* c1w = (const float*)d_in[11];
    const float* c1b = (const float*)d_in[12];
    const float* c2w = (const float*)d_in[13];
    const float* c2b = (const float*)d_in[14];
    const float* ow = (const float*)d_in[15];
    const float* ob = (const float*)d_in[16];

    char* ws = (char*)d_ws;
    size_t off = 0;
    auto alloc = [&](size_t bytes) {
        size_t r = off;
        off += (bytes + 255) & ~(size_t)255;
        return r;
    };
    int* deg_i = (int*)(ws + alloc((size_t)NT * 4));
    int* rowst = (int*)(ws + alloc((size_t)NT * 4));
    float* degf = (float*)(ws + alloc((size_t)NT * 4));
    int* csr = (int*)(ws + alloc((size_t)B * E_PAD * 4));
    float* tA = (float*)(ws + alloc((size_t)(NT + 1) * 32 * 4));  // +1 zero sentinel row
    float* tB = (float*)(ws + alloc((size_t)(NT + 1) * 32 * 4));
    float* hc1 = (float*)(ws + alloc((size_t)NT * 32 * 4));
    float* hc2 = (float*)(ws + alloc((size_t)NT * 32 * 4));
    float* hc3 = (float*)(ws + alloc((size_t)NT * 32 * 4));
    float* t4 = (float*)(ws + alloc((size_t)(NT + 1) * 4));
    float* h4 = (float*)(ws + alloc((size_t)NT * 4));

    build_csr<<<B, 1024, 0, stream>>>(esrc, edst, csr, rowst, deg_i, degf, tA, tB, t4);

    gemm_t<F_INN><<<NT / 128, 256, 0, stream>>>(node_feat, W1, tA);
    agg_f<32><<<8 * NB_G * 8, 256, 0, stream>>>(tA, csr, rowst, deg_i, degf, b1, W2, hc1, tB);
    agg_f<32><<<8 * NB_G * 8, 256, 0, stream>>>(tB, csr, rowst, deg_i, degf, b2, W3, hc2, tA);
    agg_f<1><<<8 * NB_G * 8, 256, 0, stream>>>(tA, csr, rowst, deg_i, degf, b3, W4, hc3, t4);
    agg1f<<<(NT + 255) / 256, 256, 0, stream>>>(t4, csr, rowst, deg_i, degf, b4, h4);

    sort_head<<<B, 512, 0, stream>>>(hc1, hc2, hc3, h4, c1w, c1b, c2w, c2b, ow, ob, (float*)d_out);
}